// Round 1
// 2250.751 us; speedup vs baseline: 1.1302x; 1.1302x over previous
//
#include <hip/hip_runtime.h>
#include <cstdint>
#include <cstddef>

// ---------------------------------------------------------------------------
// dims
#define BB 16
#define TT 200
#define SS 100
#define EE 256
#define HH 8
#define LL 2
#define FF 1024
#define VV 50000
#define DTXT 768
#define DIMG 512
#define GHH 64
#define MROWS (BB * TT)   // 3200
#define MENC  (BB * SS)   // 1600

using bf16x8 = __attribute__((ext_vector_type(8))) short;   // 8 bf16
using f32x4  = __attribute__((ext_vector_type(4))) float;

// fp32 -> bf16 RTNE (bit trick; inputs are sane, NaN not a concern)
__device__ __forceinline__ short f2bf(float f) {
    unsigned u = __float_as_uint(f);
    u += 0x7fffu + ((u >> 16) & 1u);
    return (short)(u >> 16);
}

// ---------------------------------------------------------------------------
// transpose fp32 [K,N] -> bf16 [N,K]  (weight prep)
__global__ __launch_bounds__(256)
void k_transpose_bf16(const float* __restrict__ in, short* __restrict__ out, int K, int N) {
    __shared__ float tile[32][33];
    int n0 = blockIdx.x * 32, k0 = blockIdx.y * 32;
    for (int i = threadIdx.y; i < 32; i += 8) {
        int k = k0 + i, n = n0 + threadIdx.x;
        tile[i][threadIdx.x] = (k < K && n < N) ? in[(size_t)k * N + n] : 0.f;
    }
    __syncthreads();
    for (int i = threadIdx.y; i < 32; i += 8) {
        int n = n0 + i, k = k0 + threadIdx.x;
        if (n < N && k < K) out[(size_t)n * K + k] = f2bf(tile[threadIdx.x][i]);
    }
}

// ---------------------------------------------------------------------------
// cast rows fp32 -> bf16, optional row gather (idx).  one block per out row.
__global__ __launch_bounds__(256)
void k_cast_rows(const float* __restrict__ in, int ldin, const int* __restrict__ idx,
                 short* __restrict__ out, int cols) {
    int r = blockIdx.x;
    int src = idx ? idx[r] : r;
    const float4* ip = (const float4*)(in + (size_t)src * ldin);
    short* op = out + (size_t)r * cols;
    for (int j = threadIdx.x; j * 4 < cols; j += blockDim.x) {
        float4 u = ip[j];
        short4 s;
        s.x = f2bf(u.x); s.y = f2bf(u.y); s.z = f2bf(u.z); s.w = f2bf(u.w);
        *(short4*)(op + j * 4) = s;
    }
}

// ---------------------------------------------------------------------------
// bf16 MFMA GEMM:  C[M,N](f32, opt) / Cb[M,N](bf16, opt) =
//     act( A[M,K](bf16) @ Bt[N,K](bf16)^T + bias )
// block = 256 (4 waves), block tile 128x128, wave tile 64x64 = 4x4 MFMA frags.
// LDS: double-buffered k-major tiles  ls[buf][kg][row][8]  (kg = k/8 within BK=64).
//   - staged with global_load_lds width=16: chunk c = wave*4+i covers
//     kg=c>>1, rows (c&1)*64 + lane  -> LDS dest is linear in lane (required).
//   - MFMA frag read: lane reads ls[kk*4+lq][row + lr][0..7], addr/16 mod 8 = row%8
//     -> 8 chunks per bank-quad = LDS minimum, conflict-free-optimal.
// A frag: lane holds A[m = lr][k = lq*8 + j]; B frag: B[k = lq*8+j][n = lr];
// D: reg i -> row=(lq)*4+i, col=lr  [verified layout per guide m89/m91]
__global__ __launch_bounds__(256, 2)
void k_gemm_bf16(const short* __restrict__ A, int lda,
                 const short* __restrict__ Bt, int ldb,
                 const float* __restrict__ bias,
                 float* __restrict__ C, short* __restrict__ Cb, int ldc,
                 int M, int N, int K, int dorelu) {
    __shared__ short lsa[2][8][128][8];   // 32 KiB
    __shared__ short lsb[2][8][128][8];   // 32 KiB
    int tid  = threadIdx.x;
    int wave = tid >> 6, lane = tid & 63;
    int lr = lane & 15, lq = lane >> 4;
    int wm = (wave >> 1) * 64, wn = (wave & 1) * 64;
    int mblk = blockIdx.y * 128, nblk = blockIdx.x * 128;

    // per-chunk per-lane global pointers (advance by 64 elems = 128 B per k-step)
    const short* pA[4];
    const short* pB[4];
#pragma unroll
    for (int i = 0; i < 4; ++i) {
        int c = wave * 4 + i;
        int kg = c >> 1, half = (c & 1) * 64;
        int ra = mblk + half + lane; if (ra > M - 1) ra = M - 1;
        int rb = nblk + half + lane; if (rb > N - 1) rb = N - 1;
        pA[i] = A  + (size_t)ra * lda + kg * 8;
        pB[i] = Bt + (size_t)rb * ldb + kg * 8;
    }

    auto stage = [&](int buf) {
#pragma unroll
        for (int i = 0; i < 4; ++i) {
            int c = wave * 4 + i;
            int kg = c >> 1, half = (c & 1) * 64;
            __builtin_amdgcn_global_load_lds(
                (const __attribute__((address_space(1))) void*)pA[i],
                (__attribute__((address_space(3))) void*)&lsa[buf][kg][half][0], 16, 0, 0);
            __builtin_amdgcn_global_load_lds(
                (const __attribute__((address_space(1))) void*)pB[i],
                (__attribute__((address_space(3))) void*)&lsb[buf][kg][half][0], 16, 0, 0);
            pA[i] += 64; pB[i] += 64;
        }
    };

    f32x4 acc[4][4];
#pragma unroll
    for (int a = 0; a < 4; ++a)
#pragma unroll
        for (int b = 0; b < 4; ++b)
#pragma unroll
            for (int i = 0; i < 4; ++i) acc[a][b][i] = 0.f;

    stage(0);
    __syncthreads();               // compiler drains vmcnt(0) before s_barrier

    int nk = K >> 6;               // K is always a multiple of 64 here
    for (int kt = 0; kt < nk; ++kt) {
        int cur = kt & 1;
        if (kt + 1 < nk) stage(cur ^ 1);   // prefetch next tile while computing
        bf16x8 af[2][4], bfr[2][4];
#pragma unroll
        for (int kk = 0; kk < 2; ++kk)
#pragma unroll
            for (int t = 0; t < 4; ++t) {
                af[kk][t]  = *(const bf16x8*)&lsa[cur][kk * 4 + lq][wm + t * 16 + lr][0];
                bfr[kk][t] = *(const bf16x8*)&lsb[cur][kk * 4 + lq][wn + t * 16 + lr][0];
            }
#pragma unroll
        for (int kk = 0; kk < 2; ++kk)
#pragma unroll
            for (int mt = 0; mt < 4; ++mt)
#pragma unroll
                for (int nt = 0; nt < 4; ++nt)
                    acc[mt][nt] = __builtin_amdgcn_mfma_f32_16x16x32_bf16(
                        af[kk][mt], bfr[kk][nt], acc[mt][nt], 0, 0, 0);
        __syncthreads();           // all reads of cur done + next-tile stage drained
    }

#pragma unroll
    for (int mt = 0; mt < 4; ++mt)
#pragma unroll
        for (int nt = 0; nt < 4; ++nt) {
            int col = nblk + wn + nt * 16 + lr;
            if (col >= N) continue;
            float bv = bias ? bias[col] : 0.f;
#pragma unroll
            for (int i = 0; i < 4; ++i) {
                int row = mblk + wm + mt * 16 + lq * 4 + i;
                if (row >= M) continue;
                float v = acc[mt][nt][i] + bv;
                if (dorelu) v = fmaxf(v, 0.f);
                if (C)  C[(size_t)row * ldc + col]  = v;
                if (Cb) Cb[(size_t)row * ldc + col] = f2bf(v);
            }
        }
}

// ---------------------------------------------------------------------------
// attention: one block per (b,h), 256 threads, thread t handles query row t.
// K/V staged in LDS. MODE: 0=none, 1=causal, 2=pad mask (+NEG on masked s).
// ctx output written as bf16 (only ever consumed as GEMM A operand).
template <int MODE>
__global__ __launch_bounds__(256)
void k_attn(const float* __restrict__ q, int qld,
            const float* __restrict__ k, const float* __restrict__ v, int kvld,
            const int* __restrict__ mask,
            short* __restrict__ out, int T, int Tk) {
    int b = blockIdx.z, h = blockIdx.y;
    int t = threadIdx.x;
    __shared__ float kl[TT][32];
    __shared__ float vl[TT][32];
    for (int idx = threadIdx.x; idx < Tk * 32; idx += 256) {
        int s = idx >> 5, i = idx & 31;
        kl[s][i] = k[((size_t)b * Tk + s) * kvld + h * 32 + i];
        vl[s][i] = v[((size_t)b * Tk + s) * kvld + h * 32 + i];
    }
    __syncthreads();
    if (t >= T) return;

    float qv[32];
    const float* qp = q + ((size_t)b * T + t) * qld + h * 32;
#pragma unroll
    for (int i = 0; i < 32; ++i) qv[i] = qp[i];

    float m = -INFINITY, l = 0.f, ctx[32];
#pragma unroll
    for (int i = 0; i < 32; ++i) ctx[i] = 0.f;

    int send = (MODE == 1) ? (t + 1) : Tk;
    for (int s = 0; s < send; ++s) {
        float d = 0.f;
#pragma unroll
        for (int i = 0; i < 32; ++i) d += qv[i] * kl[s][i];
        d *= 0.17677669529663687f;  // 1/sqrt(32)
        if (MODE == 2) { if (mask[b * Tk + s]) d += -1e9f; }
        if (d > m) {
            float f = __expf(m - d);
            l *= f;
#pragma unroll
            for (int i = 0; i < 32; ++i) ctx[i] *= f;
            m = d;
        }
        float p = __expf(d - m);
        l += p;
#pragma unroll
        for (int i = 0; i < 32; ++i) ctx[i] += p * vl[s][i];
    }
    float inv = 1.f / l;
    short* op = out + ((size_t)b * T + t) * EE + h * 32;
#pragma unroll
    for (int i = 0; i < 32; ++i) op[i] = f2bf(ctx[i] * inv);
}

// ---------------------------------------------------------------------------
// LayerNorm(res = a + b) with gain/beta, E=256, one block per row.
// Writes fp32 (residual chain / gate) AND bf16 copy (GEMM A operand).
__global__ __launch_bounds__(256)
void k_ln_res(const float* __restrict__ a, const float* __restrict__ bres,
              const float* __restrict__ gain, const float* __restrict__ beta,
              float* __restrict__ out, short* __restrict__ ob) {
    int row = blockIdx.x, i = threadIdx.x;
    __shared__ float red[256];
    float x = a[(size_t)row * EE + i] + bres[(size_t)row * EE + i];
    red[i] = x;
    __syncthreads();
    for (int s = 128; s > 0; s >>= 1) { if (i < s) red[i] += red[i + s]; __syncthreads(); }
    float mu = red[0] * (1.f / EE);
    __syncthreads();
    float d = x - mu;
    red[i] = d * d;
    __syncthreads();
    for (int s = 128; s > 0; s >>= 1) { if (i < s) red[i] += red[i + s]; __syncthreads(); }
    float var = red[0] * (1.f / EE);
    float r = rsqrtf(var + 1e-5f);
    float y = d * r * gain[i] + beta[i];
    out[(size_t)row * EE + i] = y;
    ob[(size_t)row * EE + i] = f2bf(y);
}

// ---------------------------------------------------------------------------
// gate: softmax(relu(x@g_w1+g_b1)@g_w2+g_b2) per row. block=64 per row.
__global__ __launch_bounds__(64)
void k_gate(const float* __restrict__ x, const float* __restrict__ w1, const float* __restrict__ b1,
            const float* __restrict__ w2, const float* __restrict__ b2, float* __restrict__ gate) {
    int row = blockIdx.x, j = threadIdx.x;
    __shared__ float xr[EE];
    __shared__ float hr[GHH];
    for (int i = j; i < EE; i += 64) xr[i] = x[(size_t)row * EE + i];
    __syncthreads();
    float acc = b1[j];
    for (int i = 0; i < EE; ++i) acc += xr[i] * w1[i * GHH + j];
    hr[j] = fmaxf(acc, 0.f);
    __syncthreads();
    if (j == 0) {
        float g[3];
        for (int c = 0; c < 3; ++c) {
            float a = b2[c];
            for (int kk = 0; kk < GHH; ++kk) a += hr[kk] * w2[kk * 3 + c];
            g[c] = a;
        }
        float mx = fmaxf(g[0], fmaxf(g[1], g[2]));
        float e0 = __expf(g[0] - mx), e1 = __expf(g[1] - mx), e2 = __expf(g[2] - mx);
        float inv = 1.f / (e0 + e1 + e2);
        gate[(size_t)row * 3 + 0] = e0 * inv;
        gate[(size_t)row * 3 + 1] = e1 * inv;
        gate[(size_t)row * 3 + 2] = e2 * inv;
    }
}

// ---------------------------------------------------------------------------
__global__ __launch_bounds__(256)
void k_embed(const int* __restrict__ ids, const float* __restrict__ item,
             const float* __restrict__ pos, float* __restrict__ out,
             short* __restrict__ xb) {
    int idx = blockIdx.x * 256 + threadIdx.x;
    if (idx >= MROWS * EE) return;
    int bt = idx >> 8, e = idx & 255;
    int t = bt % TT;
    float v = item[(size_t)ids[bt] * EE + e] * 16.f + pos[t * EE + e];
    out[idx] = v;
    xb[idx] = f2bf(v);
}

// combine experts -> bf16 only (consumed solely by the final-vocab GEMM)
__global__ __launch_bounds__(256)
void k_combine(const float* __restrict__ g, const float* __restrict__ e0,
               const float* __restrict__ e1, const float* __restrict__ e2,
               short* __restrict__ out) {
    int idx = blockIdx.x * 256 + threadIdx.x;
    if (idx >= MROWS * EE) return;
    int row = idx >> 8;
    float v = g[(size_t)row * 3] * e0[idx] + g[(size_t)row * 3 + 1] * e1[idx] + g[(size_t)row * 3 + 2] * e2[idx];
    out[idx] = f2bf(v);
}

// ---------------------------------------------------------------------------
extern "C" void kernel_launch(void* const* d_in, const int* in_sizes, int n_in,
                              void* d_out, int out_size, void* d_ws, size_t ws_size,
                              hipStream_t stream) {
    (void)in_sizes; (void)n_in; (void)out_size; (void)ws_size;

    const int*   ids      = (const int*)d_in[0];
    const float* enc      = (const float*)d_in[1];
    const int*   mask     = (const int*)d_in[2];
    const float* item_emb = (const float*)d_in[3];
    const float* pos_emb  = (const float*)d_in[4];
    const float* sa_qkv_w = (const float*)d_in[5];
    const float* sa_qkv_b = (const float*)d_in[6];
    const float* sa_out_w = (const float*)d_in[7];
    const float* sa_out_b = (const float*)d_in[8];
    const float* ca_qkv_w = (const float*)d_in[9];
    const float* ca_qkv_b = (const float*)d_in[10];
    const float* ca_out_w = (const float*)d_in[11];
    const float* ca_out_b = (const float*)d_in[12];
    const float* n1_s = (const float*)d_in[13];
    const float* n1_b = (const float*)d_in[14];
    const float* n2_s = (const float*)d_in[15];
    const float* n2_b = (const float*)d_in[16];
    const float* n3_s = (const float*)d_in[17];
    const float* n3_b = (const float*)d_in[18];
    const float* ffn_w1 = (const float*)d_in[19];
    const float* ffn_b1 = (const float*)d_in[20];
    const float* ffn_w2 = (const float*)d_in[21];
    const float* ffn_b2 = (const float*)d_in[22];
    const float* g_w1 = (const float*)d_in[23];
    const float* g_b1 = (const float*)d_in[24];
    const float* g_w2 = (const float*)d_in[25];
    const float* g_b2 = (const float*)d_in[26];
    const float* be_w = (const float*)d_in[27];
    const float* be_b = (const float*)d_in[28];
    const float* text_mat = (const float*)d_in[29];
    const float* tp_w = (const float*)d_in[30];
    const float* tp_b = (const float*)d_in[31];
    const float* ct_qkv_w = (const float*)d_in[32];
    const float* ct_qkv_b = (const float*)d_in[33];
    const float* ct_out_w = (const float*)d_in[34];
    const float* ct_out_b = (const float*)d_in[35];
    const float* ce_w1 = (const float*)d_in[36];
    const float* ce_b1 = (const float*)d_in[37];
    const float* ce_w2 = (const float*)d_in[38];
    const float* ce_b2 = (const float*)d_in[39];
    const float* img_mat = (const float*)d_in[40];
    const float* ip_w = (const float*)d_in[41];
    const float* ip_b = (const float*)d_in[42];
    const float* im_qkv_w = (const float*)d_in[43];
    const float* im_qkv_b = (const float*)d_in[44];
    const float* im_out_w = (const float*)d_in[45];
    const float* im_out_b = (const float*)d_in[46];
    const float* ie_w1 = (const float*)d_in[47];
    const float* ie_b1 = (const float*)d_in[48];
    const float* ie_w2 = (const float*)d_in[49];
    const float* ie_b2 = (const float*)d_in[50];
    const float* fin_w = (const float*)d_in[51];
    const float* fin_b = (const float*)d_in[52];
    float* out = (float*)d_out;

    // ---- workspace layout (bump allocator, 256B aligned) ----
    char* pws = (char*)d_ws;
    auto alloc = [&](size_t bytes) -> void* {
        void* r = (void*)pws;
        pws += (bytes + 255) & ~(size_t)255;
        return r;
    };
    short* wsaqkv = (short*)alloc((size_t)LL * 768 * 256 * 2);
    short* wsaout = (short*)alloc((size_t)LL * 256 * 256 * 2);
    short* wcaqkv = (short*)alloc((size_t)LL * 768 * 256 * 2);
    short* wcaout = (short*)alloc((size_t)LL * 256 * 256 * 2);
    short* wffn1  = (short*)alloc((size_t)LL * 1024 * 256 * 2);
    short* wffn2  = (short*)alloc((size_t)LL * 256 * 1024 * 2);
    short* wbe    = (short*)alloc((size_t)256 * 256 * 2);
    short* wtp    = (short*)alloc((size_t)256 * 768 * 2);
    short* wctqkv = (short*)alloc((size_t)768 * 256 * 2);
    short* wctout = (short*)alloc((size_t)256 * 256 * 2);
    short* wce1   = (short*)alloc((size_t)512 * 256 * 2);
    short* wce2   = (short*)alloc((size_t)256 * 512 * 2);
    short* wip    = (short*)alloc((size_t)256 * 512 * 2);
    short* wimqkv = (short*)alloc((size_t)768 * 256 * 2);
    short* wimout = (short*)alloc((size_t)256 * 256 * 2);
    short* wie1   = (short*)alloc((size_t)512 * 256 * 2);
    short* wie2   = (short*)alloc((size_t)256 * 512 * 2);
    short* wfin   = (short*)alloc((size_t)VV * 256 * 2);

    float* xbuf   = (float*)alloc((size_t)MROWS * 256 * 4);
    float* qkvbuf = (float*)alloc((size_t)MROWS * 768 * 4);
    float* qbuf   = (float*)alloc((size_t)MROWS * 256 * 4);
    float* kvbuf  = (float*)alloc((size_t)MROWS * 512 * 4);
    float* obuf   = (float*)alloc((size_t)MROWS * 256 * 4);
    float* gatebuf= (float*)alloc((size_t)MROWS * 4 * 4);
    float* ebeh   = (float*)alloc((size_t)MROWS * 256 * 4);
    float* etxt   = (float*)alloc((size_t)MROWS * 256 * 4);
    float* eimg   = (float*)alloc((size_t)MROWS * 256 * 4);
    // bf16 activation copies (GEMM A operands -> global_load_lds eligible)
    short* xb     = (short*)alloc((size_t)MROWS * 256 * 2);
    short* encb   = (short*)alloc((size_t)MENC * 256 * 2);
    short* ctxb   = (short*)alloc((size_t)MROWS * 256 * 2);
    short* pbh    = (short*)alloc((size_t)MROWS * 1024 * 2);
    short* thb    = (short*)alloc((size_t)MROWS * 256 * 2);
    short* obb    = (short*)alloc((size_t)MROWS * 256 * 2);
    short* hfb    = (short*)alloc((size_t)MROWS * 256 * 2);
    short* tg     = (short*)alloc((size_t)MROWS * 768 * 2);
    short* ig     = (short*)alloc((size_t)MROWS * 512 * 2);

    auto tr = [&](const float* in, short* o, int K, int N) {
        dim3 g((N + 31) / 32, (K + 31) / 32);
        k_transpose_bf16<<<g, dim3(32, 8), 0, stream>>>(in, o, K, N);
    };
    auto gemm = [&](const short* A, int lda, const short* Bt, const float* bias,
                    float* C, short* Cb, int ldc, int M, int N, int K, int relu) {
        dim3 g((N + 127) / 128, (M + 127) / 128);
        k_gemm_bf16<<<g, 256, 0, stream>>>(A, lda, Bt, K, bias, C, Cb, ldc, M, N, K, relu);
    };
    auto attn = [&](int mode, const float* q, int qld, const float* k, const float* v,
                    int kvld, const int* mk, short* o, int Tk) {
        dim3 g(1, HH, BB);
        if (mode == 0)      k_attn<0><<<g, 256, 0, stream>>>(q, qld, k, v, kvld, mk, o, TT, Tk);
        else if (mode == 1) k_attn<1><<<g, 256, 0, stream>>>(q, qld, k, v, kvld, mk, o, TT, Tk);
        else                k_attn<2><<<g, 256, 0, stream>>>(q, qld, k, v, kvld, mk, o, TT, Tk);
    };
    auto ln = [&](const float* a, const float* b, const float* gain, const float* beta,
                  float* o, short* ob) {
        k_ln_res<<<MROWS, 256, 0, stream>>>(a, b, gain, beta, o, ob);
    };

    // ---- weight prep (every call; idempotent, graph-safe) ----
    for (int l = 0; l < LL; ++l) {
        tr(sa_qkv_w + (size_t)l * 256 * 768, wsaqkv + (size_t)l * 768 * 256, 256, 768);
        tr(sa_out_w + (size_t)l * 256 * 256, wsaout + (size_t)l * 256 * 256, 256, 256);
        tr(ca_qkv_w + (size_t)l * 256 * 768, wcaqkv + (size_t)l * 768 * 256, 256, 768);
        tr(ca_out_w + (size_t)l * 256 * 256, wcaout + (size_t)l * 256 * 256, 256, 256);
        tr(ffn_w1 + (size_t)l * 256 * 1024, wffn1 + (size_t)l * 1024 * 256, 256, 1024);
        tr(ffn_w2 + (size_t)l * 1024 * 256, wffn2 + (size_t)l * 256 * 1024, 1024, 256);
    }
    tr(be_w, wbe, 256, 256);
    tr(tp_w, wtp, 768, 256);
    tr(ct_qkv_w, wctqkv, 256, 768);
    tr(ct_out_w, wctout, 256, 256);
    tr(ce_w1, wce1, 256, 512);
    tr(ce_w2, wce2, 512, 256);
    tr(ip_w, wip, 512, 256);
    tr(im_qkv_w, wimqkv, 256, 768);
    tr(im_out_w, wimout, 256, 256);
    tr(ie_w1, wie1, 256, 512);
    tr(ie_w2, wie2, 512, 256);
    tr(fin_w, wfin, 256, VV);

    // ---- activation casts (one-shot) ----
    k_cast_rows<<<MENC, 64, 0, stream>>>(enc, 256, nullptr, encb, 256);        // encoder mem
    k_cast_rows<<<MROWS, 192, 0, stream>>>(text_mat, DTXT, ids, tg, DTXT);     // text_mat[ids]
    k_cast_rows<<<MROWS, 128, 0, stream>>>(img_mat, DIMG, ids, ig, DIMG);      // img_mat[ids]

    // ---- embedding ----
    k_embed<<<(MROWS * EE + 255) / 256, 256, 0, stream>>>(ids, item_emb, pos_emb, xbuf, xb);

    // ---- decoder layers ----
    for (int l = 0; l < LL; ++l) {
        // self-attention
        gemm(xb, 256, wsaqkv + (size_t)l * 768 * 256, sa_qkv_b + (size_t)l * 768,
             qkvbuf, nullptr, 768, MROWS, 768, 256, 0);
        attn(1, qkvbuf, 768, qkvbuf + 256, qkvbuf + 512, 768, nullptr, ctxb, TT);
        gemm(ctxb, 256, wsaout + (size_t)l * 256 * 256, sa_out_b + (size_t)l * 256,
             obuf, nullptr, 256, MROWS, 256, 256, 0);
        ln(xbuf, obuf, n1_s + (size_t)l * 256, n1_b + (size_t)l * 256, xbuf, xb);
        // cross-attention (encoder memory)
        gemm(xb, 256, wcaqkv + (size_t)l * 768 * 256, ca_qkv_b + (size_t)l * 768,
             qbuf, nullptr, 256, MROWS, 256, 256, 0);
        gemm(encb, 256, wcaqkv + (size_t)l * 768 * 256 + 256 * 256,
             ca_qkv_b + (size_t)l * 768 + 256, kvbuf, nullptr, 512, MENC, 512, 256, 0);
        attn(2, qbuf, 256, kvbuf, kvbuf + 256, 512, mask, ctxb, SS);
        gemm(ctxb, 256, wcaout + (size_t)l * 256 * 256, ca_out_b + (size_t)l * 256,
             obuf, nullptr, 256, MROWS, 256, 256, 0);
        ln(xbuf, obuf, n2_s + (size_t)l * 256, n2_b + (size_t)l * 256, xbuf, xb);
        // FFN (hidden kept bf16-only: consumed only as ffn2's A operand)
        gemm(xb, 256, wffn1 + (size_t)l * 1024 * 256, ffn_b1 + (size_t)l * 1024,
             nullptr, pbh, 1024, MROWS, 1024, 256, 1);
        gemm(pbh, 1024, wffn2 + (size_t)l * 256 * 1024, ffn_b2 + (size_t)l * 256,
             obuf, nullptr, 256, MROWS, 256, 1024, 0);
        ln(xbuf, obuf, n3_s + (size_t)l * 256, n3_b + (size_t)l * 256, xbuf, xb);
    }

    // ---- gate + behavior expert ----
    k_gate<<<MROWS, 64, 0, stream>>>(xbuf, g_w1, g_b1, g_w2, g_b2, gatebuf);
    gemm(xb, 256, wbe, be_b, ebeh, nullptr, 256, MROWS, 256, 256, 0);

    // ---- text expert ----
    gemm(tg, DTXT, wtp, tp_b, nullptr, thb, 256, MROWS, 256, DTXT, 0);
    gemm(xb, 256, wctqkv, ct_qkv_b, qbuf, nullptr, 256, MROWS, 256, 256, 0);
    gemm(thb, 256, wctqkv + 256 * 256, ct_qkv_b + 256, kvbuf, nullptr, 512, MROWS, 512, 256, 0);
    attn(0, qbuf, 256, kvbuf, kvbuf + 256, 512, nullptr, ctxb, TT);
    gemm(ctxb, 256, wctout, ct_out_b, nullptr, obb, 256, MROWS, 256, 256, 0);
    gemm(obb, 256, wce1, ce_b1, nullptr, pbh, 512, MROWS, 512, 256, 1);
    gemm(pbh, 512, wce2, ce_b2, etxt, nullptr, 256, MROWS, 256, 512, 0);

    // ---- image expert ----
    gemm(ig, DIMG, wip, ip_b, nullptr, thb, 256, MROWS, 256, DIMG, 0);
    gemm(xb, 256, wimqkv, im_qkv_b, qbuf, nullptr, 256, MROWS, 256, 256, 0);
    gemm(thb, 256, wimqkv + 256 * 256, im_qkv_b + 256, kvbuf, nullptr, 512, MROWS, 512, 256, 0);
    attn(0, qbuf, 256, kvbuf, kvbuf + 256, 512, nullptr, ctxb, TT);
    gemm(ctxb, 256, wimout, im_out_b, nullptr, obb, 256, MROWS, 256, 256, 0);
    gemm(obb, 256, wie1, ie_b1, nullptr, pbh, 512, MROWS, 512, 256, 1);
    gemm(pbh, 512, wie2, ie_b2, eimg, nullptr, 256, MROWS, 256, 512, 0);

    // ---- combine + final vocab projection ----
    k_combine<<<(MROWS * EE + 255) / 256, 256, 0, stream>>>(gatebuf, ebeh, etxt, eimg, hfb);
    gemm(hfb, 256, wfin, fin_b, out, nullptr, VV, MROWS, VV, 256, 0);
}